// Round 1
// baseline (1799.751 us; speedup 1.0000x reference)
//
#include <hip/hip_runtime.h>
#include <math.h>

// Problem constants (from reference)
#define B       200
#define V       40
#define FIN     16
#define H       128
#define NSW     12
#define NE      40
#define M       52      // NE + NSW
#define MLP_HID 1024
#define OUTD    104     // M + V + NSW
#define MLP_IN  6656    // (NSW + V) * H
#define ZDIM    144     // M + V + M
#define ZCDIM   132     // M + V + V

__device__ __forceinline__ float sigmoidf(float x) {
    return 1.0f / (1.0f + expf(-x));
}

// K1: layer-0 projections. x_mod (B,V,16) @ {WU0,WV0,WB0,WC0} (16x128)
__global__ void k_proj0(const float* __restrict__ x,
                        const float* __restrict__ WU, const float* __restrict__ WV,
                        const float* __restrict__ WB, const float* __restrict__ WC,
                        float* __restrict__ Ux, float* __restrict__ Vx,
                        float* __restrict__ xB, float* __restrict__ xC) {
    int bv = blockIdx.x;          // 0..B*V-1
    int h  = threadIdx.x;         // 0..127
    __shared__ float xr[FIN];
    if (h < FIN) xr[h] = x[bv * FIN + h];
    __syncthreads();
    float u = 0.f, v = 0.f, bb = 0.f, cc = 0.f;
#pragma unroll
    for (int f = 0; f < FIN; ++f) {
        float xv = xr[f];
        u  += xv * WU[f * H + h];
        v  += xv * WV[f * H + h];
        bb += xv * WB[f * H + h];
        cc += xv * WC[f * H + h];
    }
    int o = bv * H + h;
    Ux[o] = u; Vx[o] = v; xB[o] = bb; xC[o] = cc;
}

// K2: layer-0 message passing + combine. One block per batch, thread = h.
// e0 / gates only needed at the 12 switch positions (smask sparsity).
__global__ void k_comb0(const int* __restrict__ ei, const int* __restrict__ si,
                        const float* __restrict__ embed, const float* __restrict__ WA0,
                        const float* __restrict__ Ux, const float* __restrict__ Vx,
                        const float* __restrict__ xB, const float* __restrict__ xC,
                        float* __restrict__ x1, float* __restrict__ e0r) {
    int b = blockIdx.x;
    int h = threadIdx.x;
    __shared__ float msg[V][H];   // 20 KB; each thread only touches column h -> no barriers needed
    for (int i = 0; i < V; ++i) msg[i][h] = 0.f;

    // sA0[h] = embed[1,:] @ WA0[:,h]  (all switch positions have S=True)
    float sA0 = 0.f;
#pragma unroll
    for (int f = 0; f < FIN; ++f) sA0 += embed[FIN + f] * WA0[f * H + h];

    const float* Vxb = Vx + b * V * H;
    for (int e = 0; e < NE; ++e) {
        int i = ei[e], j = ei[NE + e];
        msg[i][h] += Vxb[j * H + h];
        msg[j][h] += Vxb[i * H + h];
    }
    for (int k = 0; k < NSW; ++k) {
        int i = si[k], j = si[NSW + k];
        float e0 = sA0 + xB[(b * V + i) * H + h] + xC[(b * V + j) * H + h];
        float g = sigmoidf(e0);
        msg[i][h] += g * Vxb[j * H + h];
        e0r[(b * NSW + k) * H + h] = fmaxf(e0, 0.f);   // = s1 at switch pos
    }
    for (int i = 0; i < V; ++i) {
        float val = Ux[(b * V + i) * H + h] + msg[i][h];
        x1[(b * V + i) * H + h] = fmaxf(val, 0.f);     // layer 0: no residual
    }
}

// K3: layer-1 projections (x1 @ {WU1,WV1,WB1,WC1}) and sA1 = relu(e0) @ WA1
__global__ void k_proj1(const float* __restrict__ x1, const float* __restrict__ e0r,
                        const float* __restrict__ WU, const float* __restrict__ WV,
                        const float* __restrict__ WB, const float* __restrict__ WC,
                        const float* __restrict__ WA,
                        float* __restrict__ Ux, float* __restrict__ Vx,
                        float* __restrict__ xB, float* __restrict__ xC,
                        float* __restrict__ sA1) {
    int blk = blockIdx.x;
    int h   = threadIdx.x;
    __shared__ float xr[H];
    if (blk < B * V) {
        xr[h] = x1[blk * H + h];
        __syncthreads();
        float u = 0.f, v = 0.f, bb = 0.f, cc = 0.f;
#pragma unroll 8
        for (int f = 0; f < H; ++f) {
            float xv = xr[f];
            u  += xv * WU[f * H + h];
            v  += xv * WV[f * H + h];
            bb += xv * WB[f * H + h];
            cc += xv * WC[f * H + h];
        }
        int o = blk * H + h;
        Ux[o] = u; Vx[o] = v; xB[o] = bb; xC[o] = cc;
    } else {
        int r = blk - B * V;      // 0..B*NSW-1
        xr[h] = e0r[r * H + h];
        __syncthreads();
        float a = 0.f;
#pragma unroll 8
        for (int f = 0; f < H; ++f) a += xr[f] * WA[f * H + h];
        sA1[r * H + h] = a;
    }
}

// K4: layer-1 message passing + combine (residual on x and s)
__global__ void k_comb1(const int* __restrict__ ei, const int* __restrict__ si,
                        const float* __restrict__ sA1,
                        const float* __restrict__ Ux, const float* __restrict__ Vx,
                        const float* __restrict__ xB, const float* __restrict__ xC,
                        const float* __restrict__ x1, const float* __restrict__ e0r,
                        float* __restrict__ x2, float* __restrict__ s2sw) {
    int b = blockIdx.x;
    int h = threadIdx.x;
    __shared__ float msg[V][H];
    for (int i = 0; i < V; ++i) msg[i][h] = 0.f;

    const float* Vxb = Vx + b * V * H;
    for (int e = 0; e < NE; ++e) {
        int i = ei[e], j = ei[NE + e];
        msg[i][h] += Vxb[j * H + h];
        msg[j][h] += Vxb[i * H + h];
    }
    for (int k = 0; k < NSW; ++k) {
        int i = si[k], j = si[NSW + k];
        float e1 = sA1[(b * NSW + k) * H + h] + xB[(b * V + i) * H + h] + xC[(b * V + j) * H + h];
        float g = sigmoidf(e1);
        msg[i][h] += g * Vxb[j * H + h];
        s2sw[(b * NSW + k) * H + h] = e0r[(b * NSW + k) * H + h] + fmaxf(e1, 0.f); // s1 + relu(e1)
    }
    for (int i = 0; i < V; ++i) {
        float val = Ux[(b * V + i) * H + h] + msg[i][h];
        x2[(b * V + i) * H + h] = x1[(b * V + i) * H + h] + fmaxf(val, 0.f); // residual
    }
}

// K5: hidden = relu(mlp_in @ W1 + b1); mlp_in = [s2sw (1536) | x2 (5120)] per batch
#define TB 8
__global__ void k_mlp1(const float* __restrict__ s2sw, const float* __restrict__ x2,
                       const float* __restrict__ W1, const float* __restrict__ b1,
                       float* __restrict__ hidden) {
    int tid = threadIdx.x;                 // 0..127
    int o   = blockIdx.x * 128 + tid;      // output column
    int b0  = blockIdx.y * TB;             // batch tile
    __shared__ float lin[TB][128];
    float acc[TB];
#pragma unroll
    for (int t = 0; t < TB; ++t) acc[t] = 0.f;

    for (int c0 = 0; c0 < MLP_IN; c0 += 128) {
        __syncthreads();
        int c = c0 + tid;
#pragma unroll
        for (int t = 0; t < TB; ++t) {
            int b = b0 + t;
            lin[t][tid] = (c < NSW * H) ? s2sw[b * NSW * H + c]
                                        : x2[b * V * H + (c - NSW * H)];
        }
        __syncthreads();
#pragma unroll 8
        for (int cc = 0; cc < 128; ++cc) {
            float w = W1[(c0 + cc) * MLP_HID + o];
#pragma unroll
            for (int t = 0; t < TB; ++t) acc[t] += lin[t][cc] * w;
        }
    }
#pragma unroll
    for (int t = 0; t < TB; ++t)
        hidden[(b0 + t) * MLP_HID + o] = fmaxf(acc[t] + b1[o], 0.f);
}

// K6: out = hidden @ W2 + b2, then the graph-topology postprocessing + write z, zc
__global__ void k_out(const float* __restrict__ hidden, const float* __restrict__ W2,
                      const float* __restrict__ b2, const float* __restrict__ A,
                      const float* __restrict__ x_mod, float* __restrict__ outp) {
    int b   = blockIdx.x;
    int tid = threadIdx.x;   // 128 threads
    __shared__ float hid[MLP_HID];
    __shared__ float o[OUTD];
    __shared__ float gt[M], vv[V], pfc[M], qfc[M];

    for (int c = tid; c < MLP_HID; c += 128) hid[c] = hidden[b * MLP_HID + c];
    __syncthreads();

    if (tid < OUTD) {
        float acc = b2[tid];
        for (int c = 0; c < MLP_HID; ++c) acc += hid[c] * W2[c * OUTD + tid];
        o[tid] = acc;
    }
    __syncthreads();

    if (tid < M) {
        // graph_topo: first NE cols = 1, last NSW = sigmoid(out[:, 92+..])
        float g = (tid < M - NSW) ? 1.0f : sigmoidf(o[M + V + (tid - (M - NSW))]);
        gt[tid]  = g;
        pfc[tid] = g * o[tid];          // p_fc = graph_topo * out[:, :M]
    }
    if (tid < V) vv[tid] = (tid == 0) ? 1.0f : o[M + tid];   // v with v[0]=1
    __syncthreads();

    if (tid < M) {
        float acc = 0.f;
        for (int x = 0; x < V; ++x) acc += vv[x] * A[x * M + tid];
        qfc[tid] = gt[tid] * acc;       // q_fc = graph_topo * (v @ A)
    }
    __syncthreads();

    // z = [p_fc | v | graph_topo]   (B,144)
    float* zb = outp + b * ZDIM;
    if (tid < M) zb[tid]         = pfc[tid];
    if (tid < V) zb[M + tid]     = vv[tid];
    if (tid < M) zb[M + V + tid] = gt[tid];

    // zc = [q_fc | pg | qg]  (B,132), appended after all z rows
    float* zcb = outp + B * ZDIM + b * ZCDIM;
    if (tid < M) zcb[tid] = qfc[tid];
    if (tid < V) {
        float accp = 0.f, accq = 0.f;
        for (int m = 0; m < M; ++m) {
            float a = A[tid * M + m];
            accp += a * pfc[m];
            accq += a * qfc[m];
        }
        zcb[M + tid]     = x_mod[(b * V + tid) * FIN + 0] + accp;  // pg
        zcb[M + V + tid] = x_mod[(b * V + tid) * FIN + 1] + accq;  // qg
    }
}

extern "C" void kernel_launch(void* const* d_in, const int* in_sizes, int n_in,
                              void* d_out, int out_size, void* d_ws, size_t ws_size,
                              hipStream_t stream) {
    const float* x_mod = (const float*)d_in[0];
    const int*   ei    = (const int*)d_in[1];   // (B,2,NE); use ei[0]
    const int*   si    = (const int*)d_in[2];   // (B,2,NSW); use si[0]
    const float* A     = (const float*)d_in[3];
    const float* embed = (const float*)d_in[4];
    const float* WU0   = (const float*)d_in[5];
    const float* WV0   = (const float*)d_in[6];
    const float* WA0   = (const float*)d_in[7];
    const float* WB0   = (const float*)d_in[8];
    const float* WC0   = (const float*)d_in[9];
    const float* WU1   = (const float*)d_in[10];
    const float* WV1   = (const float*)d_in[11];
    const float* WA1   = (const float*)d_in[12];
    const float* WB1   = (const float*)d_in[13];
    const float* WC1   = (const float*)d_in[14];
    const float* W1    = (const float*)d_in[15];
    const float* b1    = (const float*)d_in[16];
    const float* W2    = (const float*)d_in[17];
    const float* b2    = (const float*)d_in[18];
    float* out = (float*)d_out;

    // Workspace layout (floats) — total ~7.27M floats ~= 29 MB
    float* ws   = (float*)d_ws;
    float* Ux   = ws;                    // B*V*H
    float* Vx   = Ux   + B * V * H;
    float* xB   = Vx   + B * V * H;
    float* xC   = xB   + B * V * H;
    float* x1   = xC   + B * V * H;
    float* x2   = x1   + B * V * H;
    float* e0r  = x2   + B * V * H;      // B*NSW*H  (relu(e0) at switch pos = s1_sw)
    float* sA1  = e0r  + B * NSW * H;    // B*NSW*H
    float* s2sw = sA1  + B * NSW * H;    // B*NSW*H
    float* hidden = s2sw + B * NSW * H;  // B*MLP_HID

    k_proj0<<<B * V, H, 0, stream>>>(x_mod, WU0, WV0, WB0, WC0, Ux, Vx, xB, xC);
    k_comb0<<<B, H, 0, stream>>>(ei, si, embed, WA0, Ux, Vx, xB, xC, x1, e0r);
    k_proj1<<<B * V + B * NSW, H, 0, stream>>>(x1, e0r, WU1, WV1, WB1, WC1, WA1,
                                               Ux, Vx, xB, xC, sA1);
    k_comb1<<<B, H, 0, stream>>>(ei, si, sA1, Ux, Vx, xB, xC, x1, e0r, x2, s2sw);
    k_mlp1<<<dim3(MLP_HID / 128, B / TB), 128, 0, stream>>>(s2sw, x2, W1, b1, hidden);
    k_out<<<B, 128, 0, stream>>>(hidden, W2, b2, A, x_mod, out);
}

// Round 2
// 232.411 us; speedup vs baseline: 7.7438x; 7.7438x over previous
//
#include <hip/hip_runtime.h>
#include <math.h>

// Problem constants (from reference)
#define B       200
#define V       40
#define FIN     16
#define H       128
#define NSW     12
#define NE      40
#define M       52      // NE + NSW
#define MLP_HID 1024
#define OUTD    104     // M + V + NSW
#define MLP_IN  6656    // (NSW + V) * H
#define ZDIM    144     // M + V + M
#define ZCDIM   132     // M + V + V

// MLP1 split-K config
#define KC      512     // K-chunk per block
#define NCH     13      // 6656 / 512
#define TBATCH  8       // batches per block (register tile)
#define CPB     256     // cols per block (1 per thread)

__device__ __forceinline__ float sigmoidf(float x) {
    return 1.0f / (1.0f + expf(-x));
}

// K1: layer-0 projections. x_mod (B,V,16) @ {WU0,WV0,WB0,WC0} (16x128)
__global__ void k_proj0(const float* __restrict__ x,
                        const float* __restrict__ WU, const float* __restrict__ WV,
                        const float* __restrict__ WB, const float* __restrict__ WC,
                        float* __restrict__ Ux, float* __restrict__ Vx,
                        float* __restrict__ xB, float* __restrict__ xC) {
    int bv = blockIdx.x;          // 0..B*V-1
    int h  = threadIdx.x;         // 0..127
    __shared__ float xr[FIN];
    if (h < FIN) xr[h] = x[bv * FIN + h];
    __syncthreads();
    float u = 0.f, v = 0.f, bb = 0.f, cc = 0.f;
#pragma unroll
    for (int f = 0; f < FIN; ++f) {
        float xv = xr[f];
        u  += xv * WU[f * H + h];
        v  += xv * WV[f * H + h];
        bb += xv * WB[f * H + h];
        cc += xv * WC[f * H + h];
    }
    int o = bv * H + h;
    Ux[o] = u; Vx[o] = v; xB[o] = bb; xC[o] = cc;
}

// K2: layer-0 message passing + combine. One block per batch, thread = h.
__global__ void k_comb0(const int* __restrict__ ei, const int* __restrict__ si,
                        const float* __restrict__ embed, const float* __restrict__ WA0,
                        const float* __restrict__ Ux, const float* __restrict__ Vx,
                        const float* __restrict__ xB, const float* __restrict__ xC,
                        float* __restrict__ x1, float* __restrict__ e0r) {
    int b = blockIdx.x;
    int h = threadIdx.x;
    __shared__ float msg[V][H];   // each thread only touches column h
    for (int i = 0; i < V; ++i) msg[i][h] = 0.f;

    float sA0 = 0.f;
#pragma unroll
    for (int f = 0; f < FIN; ++f) sA0 += embed[FIN + f] * WA0[f * H + h];

    const float* Vxb = Vx + b * V * H;
    for (int e = 0; e < NE; ++e) {
        int i = ei[e], j = ei[NE + e];
        msg[i][h] += Vxb[j * H + h];
        msg[j][h] += Vxb[i * H + h];
    }
    for (int k = 0; k < NSW; ++k) {
        int i = si[k], j = si[NSW + k];
        float e0 = sA0 + xB[(b * V + i) * H + h] + xC[(b * V + j) * H + h];
        float g = sigmoidf(e0);
        msg[i][h] += g * Vxb[j * H + h];
        e0r[(b * NSW + k) * H + h] = fmaxf(e0, 0.f);
    }
    for (int i = 0; i < V; ++i) {
        float val = Ux[(b * V + i) * H + h] + msg[i][h];
        x1[(b * V + i) * H + h] = fmaxf(val, 0.f);
    }
}

// K3: layer-1 projections (x1 @ {WU1,WV1,WB1,WC1}) and sA1 = relu(e0) @ WA1
__global__ void k_proj1(const float* __restrict__ x1, const float* __restrict__ e0r,
                        const float* __restrict__ WU, const float* __restrict__ WV,
                        const float* __restrict__ WB, const float* __restrict__ WC,
                        const float* __restrict__ WA,
                        float* __restrict__ Ux, float* __restrict__ Vx,
                        float* __restrict__ xB, float* __restrict__ xC,
                        float* __restrict__ sA1) {
    int blk = blockIdx.x;
    int h   = threadIdx.x;
    __shared__ float xr[H];
    if (blk < B * V) {
        xr[h] = x1[blk * H + h];
        __syncthreads();
        float u = 0.f, v = 0.f, bb = 0.f, cc = 0.f;
#pragma unroll 8
        for (int f = 0; f < H; ++f) {
            float xv = xr[f];
            u  += xv * WU[f * H + h];
            v  += xv * WV[f * H + h];
            bb += xv * WB[f * H + h];
            cc += xv * WC[f * H + h];
        }
        int o = blk * H + h;
        Ux[o] = u; Vx[o] = v; xB[o] = bb; xC[o] = cc;
    } else {
        int r = blk - B * V;      // 0..B*NSW-1
        xr[h] = e0r[r * H + h];
        __syncthreads();
        float a = 0.f;
#pragma unroll 8
        for (int f = 0; f < H; ++f) a += xr[f] * WA[f * H + h];
        sA1[r * H + h] = a;
    }
}

// K4: layer-1 message passing + combine (residual on x and s)
__global__ void k_comb1(const int* __restrict__ ei, const int* __restrict__ si,
                        const float* __restrict__ sA1,
                        const float* __restrict__ Ux, const float* __restrict__ Vx,
                        const float* __restrict__ xB, const float* __restrict__ xC,
                        const float* __restrict__ x1, const float* __restrict__ e0r,
                        float* __restrict__ x2, float* __restrict__ s2sw) {
    int b = blockIdx.x;
    int h = threadIdx.x;
    __shared__ float msg[V][H];
    for (int i = 0; i < V; ++i) msg[i][h] = 0.f;

    const float* Vxb = Vx + b * V * H;
    for (int e = 0; e < NE; ++e) {
        int i = ei[e], j = ei[NE + e];
        msg[i][h] += Vxb[j * H + h];
        msg[j][h] += Vxb[i * H + h];
    }
    for (int k = 0; k < NSW; ++k) {
        int i = si[k], j = si[NSW + k];
        float e1 = sA1[(b * NSW + k) * H + h] + xB[(b * V + i) * H + h] + xC[(b * V + j) * H + h];
        float g = sigmoidf(e1);
        msg[i][h] += g * Vxb[j * H + h];
        s2sw[(b * NSW + k) * H + h] = e0r[(b * NSW + k) * H + h] + fmaxf(e1, 0.f);
    }
    for (int i = 0; i < V; ++i) {
        float val = Ux[(b * V + i) * H + h] + msg[i][h];
        x2[(b * V + i) * H + h] = x1[(b * V + i) * H + h] + fmaxf(val, 0.f);
    }
}

// K5a: split-K partial GEMM: partial[kc][b][o] = sum_{k in chunk} mlp_in[b][k] * W1[k][o]
// grid (MLP_HID/CPB, B/TBATCH, NCH), block 256 (1 col per thread)
__global__ __launch_bounds__(256)
void k_mlp1_part(const float* __restrict__ s2sw, const float* __restrict__ x2,
                 const float* __restrict__ W1, float* __restrict__ partial) {
    int tid  = threadIdx.x;                       // 0..255
    int col  = blockIdx.x * CPB + tid;            // output column
    int b0   = blockIdx.y * TBATCH;               // batch tile
    int kbase = blockIdx.z * KC;                  // K-chunk base

    __shared__ float lin[TBATCH][KC];             // 16 KB
    // cooperative staged load of mlp_in slice (concat of s2sw | x2)
    for (int idx = tid; idx < TBATCH * KC; idx += 256) {
        int t = idx >> 9;            // /KC
        int k = idx & (KC - 1);
        int c = kbase + k;
        int b = b0 + t;
        lin[t][k] = (c < NSW * H) ? s2sw[b * NSW * H + c]
                                  : x2[b * V * H + (c - NSW * H)];
    }
    __syncthreads();

    float acc[TBATCH];
#pragma unroll
    for (int t = 0; t < TBATCH; ++t) acc[t] = 0.f;

    const float* w = W1 + (size_t)kbase * MLP_HID + col;
    for (int k = 0; k < KC; k += 4) {
        float w0 = w[(size_t)(k + 0) * MLP_HID];
        float w1 = w[(size_t)(k + 1) * MLP_HID];
        float w2 = w[(size_t)(k + 2) * MLP_HID];
        float w3 = w[(size_t)(k + 3) * MLP_HID];
#pragma unroll
        for (int t = 0; t < TBATCH; ++t) {
            float4 l4 = *(const float4*)&lin[t][k];   // broadcast, conflict-free
            acc[t] += l4.x * w0 + l4.y * w1 + l4.z * w2 + l4.w * w3;
        }
    }
#pragma unroll
    for (int t = 0; t < TBATCH; ++t)
        partial[((size_t)blockIdx.z * B + (b0 + t)) * MLP_HID + col] = acc[t];
}

// K5b: reduce split-K partials + bias + relu
__global__ void k_mlp1_red(const float* __restrict__ partial, const float* __restrict__ b1,
                           float* __restrict__ hidden) {
    int i = blockIdx.x * 256 + threadIdx.x;
    if (i >= B * MLP_HID) return;
    float s = b1[i & (MLP_HID - 1)];
#pragma unroll
    for (int kc = 0; kc < NCH; ++kc) s += partial[(size_t)kc * B * MLP_HID + i];
    hidden[i] = fmaxf(s, 0.f);
}

// K6: out = hidden @ W2 + b2, then graph-topology postprocessing + write z, zc
__global__ void k_out(const float* __restrict__ hidden, const float* __restrict__ W2,
                      const float* __restrict__ b2, const float* __restrict__ A,
                      const float* __restrict__ x_mod, float* __restrict__ outp) {
    int b   = blockIdx.x;
    int tid = threadIdx.x;   // 128 threads
    __shared__ float hid[MLP_HID];
    __shared__ float o[OUTD];
    __shared__ float gt[M], vv[V], pfc[M], qfc[M];

    for (int c = tid; c < MLP_HID; c += 128) hid[c] = hidden[b * MLP_HID + c];
    __syncthreads();

    if (tid < OUTD) {
        float acc = b2[tid];
        for (int c = 0; c < MLP_HID; ++c) acc += hid[c] * W2[c * OUTD + tid];
        o[tid] = acc;
    }
    __syncthreads();

    if (tid < M) {
        float g = (tid < M - NSW) ? 1.0f : sigmoidf(o[M + V + (tid - (M - NSW))]);
        gt[tid]  = g;
        pfc[tid] = g * o[tid];
    }
    if (tid < V) vv[tid] = (tid == 0) ? 1.0f : o[M + tid];
    __syncthreads();

    if (tid < M) {
        float acc = 0.f;
        for (int x = 0; x < V; ++x) acc += vv[x] * A[x * M + tid];
        qfc[tid] = gt[tid] * acc;
    }
    __syncthreads();

    float* zb = outp + b * ZDIM;
    if (tid < M) zb[tid]         = pfc[tid];
    if (tid < V) zb[M + tid]     = vv[tid];
    if (tid < M) zb[M + V + tid] = gt[tid];

    float* zcb = outp + B * ZDIM + b * ZCDIM;
    if (tid < M) zcb[tid] = qfc[tid];
    if (tid < V) {
        float accp = 0.f, accq = 0.f;
        for (int m = 0; m < M; ++m) {
            float a = A[tid * M + m];
            accp += a * pfc[m];
            accq += a * qfc[m];
        }
        zcb[M + tid]     = x_mod[(b * V + tid) * FIN + 0] + accp;
        zcb[M + V + tid] = x_mod[(b * V + tid) * FIN + 1] + accq;
    }
}

extern "C" void kernel_launch(void* const* d_in, const int* in_sizes, int n_in,
                              void* d_out, int out_size, void* d_ws, size_t ws_size,
                              hipStream_t stream) {
    const float* x_mod = (const float*)d_in[0];
    const int*   ei    = (const int*)d_in[1];
    const int*   si    = (const int*)d_in[2];
    const float* A     = (const float*)d_in[3];
    const float* embed = (const float*)d_in[4];
    const float* WU0   = (const float*)d_in[5];
    const float* WV0   = (const float*)d_in[6];
    const float* WA0   = (const float*)d_in[7];
    const float* WB0   = (const float*)d_in[8];
    const float* WC0   = (const float*)d_in[9];
    const float* WU1   = (const float*)d_in[10];
    const float* WV1   = (const float*)d_in[11];
    const float* WA1   = (const float*)d_in[12];
    const float* WB1   = (const float*)d_in[13];
    const float* WC1   = (const float*)d_in[14];
    const float* W1    = (const float*)d_in[15];
    const float* b1    = (const float*)d_in[16];
    const float* W2    = (const float*)d_in[17];
    const float* b2    = (const float*)d_in[18];
    float* out = (float*)d_out;

    // Workspace layout (floats)
    float* ws   = (float*)d_ws;
    float* Ux   = ws;                    // B*V*H
    float* Vx   = Ux   + B * V * H;
    float* xB   = Vx   + B * V * H;
    float* xC   = xB   + B * V * H;
    float* x1   = xC   + B * V * H;
    float* x2   = x1   + B * V * H;
    float* e0r  = x2   + B * V * H;      // B*NSW*H
    float* sA1  = e0r  + B * NSW * H;    // B*NSW*H
    float* s2sw = sA1  + B * NSW * H;    // B*NSW*H
    float* hidden = s2sw + B * NSW * H;  // B*MLP_HID
    // partial (NCH*B*MLP_HID = 2.66M floats) aliases Ux..xC (4.1M floats),
    // which are dead after k_comb1.
    float* partial = Ux;

    k_proj0<<<B * V, H, 0, stream>>>(x_mod, WU0, WV0, WB0, WC0, Ux, Vx, xB, xC);
    k_comb0<<<B, H, 0, stream>>>(ei, si, embed, WA0, Ux, Vx, xB, xC, x1, e0r);
    k_proj1<<<B * V + B * NSW, H, 0, stream>>>(x1, e0r, WU1, WV1, WB1, WC1, WA1,
                                               Ux, Vx, xB, xC, sA1);
    k_comb1<<<B, H, 0, stream>>>(ei, si, sA1, Ux, Vx, xB, xC, x1, e0r, x2, s2sw);
    k_mlp1_part<<<dim3(MLP_HID / CPB, B / TBATCH, NCH), 256, 0, stream>>>(s2sw, x2, W1, partial);
    k_mlp1_red<<<(B * MLP_HID + 255) / 256, 256, 0, stream>>>(partial, b1, hidden);
    k_out<<<B, 128, 0, stream>>>(hidden, W2, b2, A, x_mod, out);
}

// Round 3
// 77.766 us; speedup vs baseline: 23.1431x; 2.9886x over previous
//
#include <hip/hip_runtime.h>
#include <math.h>

// Problem constants
#define B       200
#define V       40
#define FIN     16
#define H       128
#define NSW     12
#define NE      40
#define M       52      // NE + NSW
#define MLP_HID 1024
#define OUTD    104     // M + V + NSW
#define MLP_IN  6656    // (NSW + V) * H
#define ZDIM    144
#define ZCDIM   132

typedef __attribute__((ext_vector_type(8))) short bf16x8;
typedef __attribute__((ext_vector_type(4))) float f32x4;

__device__ __forceinline__ float sigmoidf(float x) {
    return 1.0f / (1.0f + expf(-x));
}
__device__ __forceinline__ unsigned short f2b(float x) {  // fp32 -> bf16 RNE
    unsigned int u = __float_as_uint(x);
    u += 0x7fffu + ((u >> 16) & 1u);
    return (unsigned short)(u >> 16);
}
__device__ __forceinline__ float b2f(unsigned short s) {
    return __uint_as_float(((unsigned int)s) << 16);
}

// ---------------- weight prep ----------------
// W1 (6656x1024 f32) -> W1t (1024x6656 bf16), 32x32 LDS tiles
__global__ void k_w1t(const float* __restrict__ W1, unsigned short* __restrict__ W1t) {
    int k0 = blockIdx.x * 32, n0 = blockIdx.y * 32;
    __shared__ float tile[32][33];
    int c = threadIdx.x & 31, r8 = threadIdx.x >> 5;
#pragma unroll
    for (int i = 0; i < 4; ++i) {
        int r = r8 + i * 8;
        tile[r][c] = W1[(size_t)(k0 + r) * MLP_HID + n0 + c];
    }
    __syncthreads();
#pragma unroll
    for (int i = 0; i < 4; ++i) {
        int rr = r8 + i * 8;
        W1t[(size_t)(n0 + rr) * MLP_IN + k0 + c] = f2b(tile[c][rr]);
    }
}

// {WU1,WV1,WB1,WC1,WA1} (each 128x128 [f][h]) -> Wt640[col][k], col = m*128+h, k=f
__global__ void k_wt640(const float* __restrict__ WU, const float* __restrict__ WV,
                        const float* __restrict__ WB, const float* __restrict__ WC,
                        const float* __restrict__ WA, unsigned short* __restrict__ Wt) {
    int o = blockIdx.x * 256 + threadIdx.x;
    if (o >= 640 * 128) return;
    int col = o >> 7, f = o & 127;
    int m = col >> 7, h = col & 127;
    const float* Ws = (m == 0) ? WU : (m == 1) ? WV : (m == 2) ? WB : (m == 3) ? WC : WA;
    Wt[o] = f2b(Ws[f * H + h]);
}

// ---------------- layer-0 projections ----------------
// 16 rows/block; thread t: col=t&127, mp=t>>7 handles mats {mp, mp+2}
__global__ __launch_bounds__(256) void k_proj0(const float* __restrict__ x,
        const float* __restrict__ WU, const float* __restrict__ WV,
        const float* __restrict__ WB, const float* __restrict__ WC,
        float* __restrict__ UVBC) {
    int bv0 = blockIdx.x * 16;
    int t = threadIdx.x;
    __shared__ float xs[16 * FIN];
    xs[t] = x[(size_t)bv0 * FIN + t];   // 256 = 16 rows x 16 f
    __syncthreads();
    int col = t & 127, mp = t >> 7;
    const float* w1p = mp ? WV : WU;
    const float* w2p = mp ? WC : WB;
    float a0[16], a1[16];
#pragma unroll
    for (int r = 0; r < 16; ++r) { a0[r] = 0.f; a1[r] = 0.f; }
#pragma unroll 4
    for (int f = 0; f < FIN; ++f) {
        float w0 = w1p[f * H + col];
        float w1 = w2p[f * H + col];
#pragma unroll
        for (int r = 0; r < 16; ++r) {
            float xv = xs[r * FIN + f];
            a0[r] += xv * w0;
            a1[r] += xv * w1;
        }
    }
#pragma unroll
    for (int r = 0; r < 16; ++r) {
        UVBC[(size_t)(bv0 + r) * 512 + mp * 128 + col]       = a0[r];
        UVBC[(size_t)(bv0 + r) * 512 + (mp + 2) * 128 + col] = a1[r];
    }
}

// ---------------- combine kernels (512 thr, 4 edge-subgroups) ----------------
__global__ __launch_bounds__(512) void k_comb0(const int* __restrict__ ei, const int* __restrict__ si,
        const float* __restrict__ embed, const float* __restrict__ WA0,
        const float* __restrict__ UVBC,
        unsigned short* __restrict__ x1b, unsigned short* __restrict__ e0rb) {
    int b = blockIdx.x;
    int tid = threadIdx.x;
    int h = tid & 127, sub = tid >> 7;
    __shared__ float msg[4][V][H];   // 80 KB
    for (int i = 0; i < V; ++i) msg[sub][i][h] = 0.f;

    float sA0 = 0.f;
#pragma unroll
    for (int f = 0; f < FIN; ++f) sA0 += embed[FIN + f] * WA0[f * H + h];

    const float* base = UVBC + (size_t)b * V * 512;
    for (int e = sub * 10; e < sub * 10 + 10; ++e) {
        int i = ei[e], j = ei[NE + e];
        msg[sub][i][h] += base[j * 512 + 128 + h];   // Vx[j]
        msg[sub][j][h] += base[i * 512 + 128 + h];
    }
    for (int k = sub * 3; k < sub * 3 + 3; ++k) {
        int i = si[k], j = si[NSW + k];
        float e0 = sA0 + base[i * 512 + 256 + h] + base[j * 512 + 384 + h];
        float g = sigmoidf(e0);
        msg[sub][i][h] += g * base[j * 512 + 128 + h];
        e0rb[(size_t)(b * NSW + k) * H + h] = f2b(fmaxf(e0, 0.f));
    }
    __syncthreads();
    for (int i = sub * 10; i < sub * 10 + 10; ++i) {
        float v = base[i * 512 + h] + msg[0][i][h] + msg[1][i][h] + msg[2][i][h] + msg[3][i][h];
        x1b[(size_t)(b * V + i) * H + h] = f2b(fmaxf(v, 0.f));
    }
}

__global__ __launch_bounds__(512) void k_comb1(const int* __restrict__ ei, const int* __restrict__ si,
        const float* __restrict__ sA1, const float* __restrict__ UVBC,
        const unsigned short* __restrict__ x1b, const unsigned short* __restrict__ e0rb,
        unsigned short* __restrict__ Abf) {
    int b = blockIdx.x;
    int tid = threadIdx.x;
    int h = tid & 127, sub = tid >> 7;
    __shared__ float msg[4][V][H];
    for (int i = 0; i < V; ++i) msg[sub][i][h] = 0.f;

    const float* base = UVBC + (size_t)b * V * 512;
    for (int e = sub * 10; e < sub * 10 + 10; ++e) {
        int i = ei[e], j = ei[NE + e];
        msg[sub][i][h] += base[j * 512 + 128 + h];
        msg[sub][j][h] += base[i * 512 + 128 + h];
    }
    for (int k = sub * 3; k < sub * 3 + 3; ++k) {
        int i = si[k], j = si[NSW + k];
        float e1 = sA1[(size_t)(b * NSW + k) * H + h] + base[i * 512 + 256 + h] + base[j * 512 + 384 + h];
        float g = sigmoidf(e1);
        msg[sub][i][h] += g * base[j * 512 + 128 + h];
        float s1 = b2f(e0rb[(size_t)(b * NSW + k) * H + h]);
        Abf[(size_t)b * MLP_IN + k * H + h] = f2b(s1 + fmaxf(e1, 0.f));  // s2 at switch
    }
    __syncthreads();
    for (int i = sub * 10; i < sub * 10 + 10; ++i) {
        float xh = base[i * 512 + h] + msg[0][i][h] + msg[1][i][h] + msg[2][i][h] + msg[3][i][h];
        float x2 = b2f(x1b[(size_t)(b * V + i) * H + h]) + fmaxf(xh, 0.f);  // residual
        Abf[(size_t)b * MLP_IN + NSW * H + i * H + h] = f2b(x2);
    }
}

// ---------------- generic bf16 MFMA GEMM ----------------
// C[M x N] = A[M x K](bf16,rowmajor) @ Bt[N x K](bf16,rowmajor)^T
// grid(N/64, M/64, KS); block 256 = 4 waves, wave tile 32x32 (2x2 frags)
// gridDim.z==1: write C (f32, ldc). else: write partial[z][Mrows][ldc].
__global__ __launch_bounds__(256) void k_gemm(const unsigned short* __restrict__ A,
        const unsigned short* __restrict__ Bt, float* __restrict__ C,
        float* __restrict__ partial, int K, int nk, int ldc) {
    int tid = threadIdx.x;
    int lane = tid & 63, wv = tid >> 6;
    int wr = (wv >> 1) * 32, wc = (wv & 1) * 32;
    int n0 = blockIdx.x * 64, m0 = blockIdx.y * 64;
    size_t kbase = (size_t)blockIdx.z * nk * 32;

    __shared__ __align__(16) unsigned short a_lds[64 * 40];
    __shared__ __align__(16) unsigned short b_lds[64 * 40];

    f32x4 acc00 = {0,0,0,0}, acc01 = {0,0,0,0}, acc10 = {0,0,0,0}, acc11 = {0,0,0,0};

    int srow = tid >> 2, sseg = tid & 3;
    const int4* gA = (const int4*)(A + (size_t)(m0 + srow) * K + kbase + sseg * 8);
    const int4* gB = (const int4*)(Bt + (size_t)(n0 + srow) * K + kbase + sseg * 8);
    int lws = srow * 40 + sseg * 8;

    int a_off = (wr + (lane & 15)) * 40 + (lane >> 4) * 8;
    int b_off = (wc + (lane & 15)) * 40 + (lane >> 4) * 8;

    int4 ra = gA[0], rb = gB[0];
    for (int kk = 0; kk < nk; ++kk) {
        *(int4*)&a_lds[lws] = ra;
        *(int4*)&b_lds[lws] = rb;
        __syncthreads();
        if (kk + 1 < nk) { ra = gA[(kk + 1) * 4]; rb = gB[(kk + 1) * 4]; }
        bf16x8 a0 = *(const bf16x8*)&a_lds[a_off];
        bf16x8 a1 = *(const bf16x8*)&a_lds[a_off + 16 * 40];
        bf16x8 b0 = *(const bf16x8*)&b_lds[b_off];
        bf16x8 b1 = *(const bf16x8*)&b_lds[b_off + 16 * 40];
        acc00 = __builtin_amdgcn_mfma_f32_16x16x32_bf16(a0, b0, acc00, 0, 0, 0);
        acc01 = __builtin_amdgcn_mfma_f32_16x16x32_bf16(a0, b1, acc01, 0, 0, 0);
        acc10 = __builtin_amdgcn_mfma_f32_16x16x32_bf16(a1, b0, acc10, 0, 0, 0);
        acc11 = __builtin_amdgcn_mfma_f32_16x16x32_bf16(a1, b1, acc11, 0, 0, 0);
        __syncthreads();
    }

    int crow = (lane >> 4) * 4;
    int ccol = lane & 15;
    int row0 = m0 + wr + crow, row1 = row0 + 16;
    int col0 = n0 + wc + ccol, col1 = col0 + 16;
    float* dst;
    if (gridDim.z == 1) {
        dst = C;
    } else {
        dst = partial + (size_t)blockIdx.z * (gridDim.y * 64) * ldc;
    }
#pragma unroll
    for (int r = 0; r < 4; ++r) {
        dst[(size_t)(row0 + r) * ldc + col0] = acc00[r];
        dst[(size_t)(row0 + r) * ldc + col1] = acc01[r];
        dst[(size_t)(row1 + r) * ldc + col0] = acc10[r];
        dst[(size_t)(row1 + r) * ldc + col1] = acc11[r];
    }
}

// reduce mlp1 split-K partials + bias + relu  (rows 0..207)
__global__ void k_mred(const float* __restrict__ partial, const float* __restrict__ b1,
                       float* __restrict__ hidden) {
    int i = blockIdx.x * 256 + threadIdx.x;   // < 208*1024
    float s = b1[i & (MLP_HID - 1)];
#pragma unroll
    for (int z = 0; z < 8; ++z) s += partial[(size_t)z * 256 * MLP_HID + i];
    hidden[i] = fmaxf(s, 0.f);
}

// ---------------- output head ----------------
// split-K over hidden: grid(25 batch-tiles, 8 k-chunks), 128 thr
__global__ __launch_bounds__(128) void k_out_part(const float* __restrict__ hidden,
        const float* __restrict__ W2, float* __restrict__ partial2) {
    int col = threadIdx.x;
    int b0 = blockIdx.x * 8;
    int kc = blockIdx.y;
    __shared__ float lin[8][128];
    for (int idx = threadIdx.x; idx < 8 * 128; idx += 128) {
        int t = idx >> 7, k = idx & 127;
        lin[t][k] = hidden[(size_t)(b0 + t) * MLP_HID + kc * 128 + k];
    }
    __syncthreads();
    if (col >= OUTD) return;
    float acc[8];
#pragma unroll
    for (int t = 0; t < 8; ++t) acc[t] = 0.f;
    const float* w = W2 + (size_t)(kc * 128) * OUTD + col;
#pragma unroll 4
    for (int k = 0; k < 128; ++k) {
        float wv = w[(size_t)k * OUTD];
#pragma unroll
        for (int t = 0; t < 8; ++t) acc[t] += lin[t][k] * wv;
    }
#pragma unroll
    for (int t = 0; t < 8; ++t)
        partial2[((size_t)kc * B + b0 + t) * OUTD + col] = acc[t];
}

__global__ __launch_bounds__(128) void k_fin(const float* __restrict__ partial2,
        const float* __restrict__ b2, const float* __restrict__ A,
        const float* __restrict__ x_mod, float* __restrict__ outp) {
    int b = blockIdx.x;
    int tid = threadIdx.x;
    __shared__ float o[OUTD];
    __shared__ float gt[M], vv[V], pfc[M], qfc[M];

    if (tid < OUTD) {
        float s = b2[tid];
#pragma unroll
        for (int kc = 0; kc < 8; ++kc) s += partial2[((size_t)kc * B + b) * OUTD + tid];
        o[tid] = s;
    }
    __syncthreads();

    if (tid < M) {
        float g = (tid < M - NSW) ? 1.0f : sigmoidf(o[M + V + (tid - (M - NSW))]);
        gt[tid] = g;
        pfc[tid] = g * o[tid];
    }
    if (tid < V) vv[tid] = (tid == 0) ? 1.0f : o[M + tid];
    __syncthreads();

    if (tid < M) {
        float acc = 0.f;
        for (int x = 0; x < V; ++x) acc += vv[x] * A[x * M + tid];
        qfc[tid] = gt[tid] * acc;
    }
    __syncthreads();

    float* zb = outp + (size_t)b * ZDIM;
    if (tid < M) zb[tid] = pfc[tid];
    if (tid < V) zb[M + tid] = vv[tid];
    if (tid < M) zb[M + V + tid] = gt[tid];

    float* zcb = outp + (size_t)B * ZDIM + (size_t)b * ZCDIM;
    if (tid < M) zcb[tid] = qfc[tid];
    if (tid < V) {
        float accp = 0.f, accq = 0.f;
        for (int m = 0; m < M; ++m) {
            float a = A[tid * M + m];
            accp += a * pfc[m];
            accq += a * qfc[m];
        }
        zcb[M + tid]     = x_mod[(size_t)(b * V + tid) * FIN + 0] + accp;
        zcb[M + V + tid] = x_mod[(size_t)(b * V + tid) * FIN + 1] + accq;
    }
}

extern "C" void kernel_launch(void* const* d_in, const int* in_sizes, int n_in,
                              void* d_out, int out_size, void* d_ws, size_t ws_size,
                              hipStream_t stream) {
    const float* x_mod = (const float*)d_in[0];
    const int*   ei    = (const int*)d_in[1];
    const int*   si    = (const int*)d_in[2];
    const float* A     = (const float*)d_in[3];
    const float* embed = (const float*)d_in[4];
    const float* WU0   = (const float*)d_in[5];
    const float* WV0   = (const float*)d_in[6];
    const float* WA0   = (const float*)d_in[7];
    const float* WB0   = (const float*)d_in[8];
    const float* WC0   = (const float*)d_in[9];
    const float* WU1   = (const float*)d_in[10];
    const float* WV1   = (const float*)d_in[11];
    const float* WA1   = (const float*)d_in[12];
    const float* WB1   = (const float*)d_in[13];
    const float* WC1   = (const float*)d_in[14];
    const float* W1    = (const float*)d_in[15];
    const float* b1    = (const float*)d_in[16];
    const float* W2    = (const float*)d_in[17];
    const float* b2    = (const float*)d_in[18];
    float* out = (float*)d_out;

    // Workspace layout (float offsets); total ~9.54M floats = 38.2 MB
    float* ws = (float*)d_ws;
    float*          UVBC  = ws;                          // 8000*512 = 4,096,000 (reused L0 then L1)
    float*          hidden   = ws;                       // 256*1024 (alias; UVBC dead by then)
    float*          partialM = ws + 262144;              // 8*256*1024 = 2,097,152 (alias)
    unsigned short* x1b   = (unsigned short*)(ws + 4096000);   // 8000*128 bf16
    unsigned short* e0rb  = (unsigned short*)(ws + 4608000);   // 2432*128 bf16 (rows 2400+ pad)
    float*          sA1   = ws + 4763648;                // 2400*128 f32
    unsigned short* Abf   = (unsigned short*)(ws + 5070848);   // 256*6656 bf16 (rows 200+ pad)
    unsigned short* W1t   = (unsigned short*)(ws + 5922816);   // 1024*6656 bf16
    unsigned short* Wt640 = (unsigned short*)(ws + 9330688);   // 640*128 bf16
    float*          partial2 = ws + 9371648;             // 8*200*104 f32

    k_w1t<<<dim3(MLP_IN / 32, MLP_HID / 32), 256, 0, stream>>>(W1, W1t);
    k_wt640<<<320, 256, 0, stream>>>(WU1, WV1, WB1, WC1, WA1, Wt640);

    k_proj0<<<B * V / 16, 256, 0, stream>>>(x_mod, WU0, WV0, WB0, WC0, UVBC);
    k_comb0<<<B, 512, 0, stream>>>(ei, si, embed, WA0, UVBC, x1b, e0rb);

    // proj1: (8000x128) @ (128x512) -> UVBC, grid(8,125,1)
    k_gemm<<<dim3(8, 125, 1), 256, 0, stream>>>(x1b, Wt640, UVBC, nullptr, H, 4, 512);
    // sA1: (2432x128) @ (128x128) -> sA1, grid(2,38,1)
    k_gemm<<<dim3(2, 38, 1), 256, 0, stream>>>(e0rb, Wt640 + 512 * 128, sA1, nullptr, H, 4, 128);

    k_comb1<<<B, 512, 0, stream>>>(ei, si, sA1, UVBC, x1b, e0rb, Abf);

    // mlp1: (256x6656) @ (6656x1024) split-K=8 -> partialM, grid(16,4,8)
    k_gemm<<<dim3(16, 4, 8), 256, 0, stream>>>(Abf, W1t, nullptr, partialM, MLP_IN, 26, MLP_HID);
    k_mred<<<208 * MLP_HID / 256, 256, 0, stream>>>(partialM, b1, hidden);

    k_out_part<<<dim3(B / 8, 8), 128, 0, stream>>>(hidden, W2, partial2);
    k_fin<<<B, 128, 0, stream>>>(partial2, b2, A, x_mod, out);
}